// Round 17
// baseline (221.284 us; speedup 1.0000x reference)
//
#include <hip/hip_runtime.h>

#define TOTAL_WORDS 10000
#define EMBED_LEN 100
#define SEQ_LEN 80
#define BATCH 4096
#define UNITS 64

typedef __attribute__((ext_vector_type(8))) short short8;
typedef __attribute__((ext_vector_type(4))) float floatx4;

// ---------- fast activations (no NaN at saturation) ----------
__device__ __forceinline__ float fast_sigmoid(float x) {
    return __builtin_amdgcn_rcpf(1.0f + __builtin_amdgcn_exp2f(-1.4426950408889634f * x));
}
__device__ __forceinline__ float fast_tanh(float x) {
    return fmaf(2.0f, __builtin_amdgcn_rcpf(1.0f + __builtin_amdgcn_exp2f(-2.8853900817779268f * x)), -1.0f);
}
// RNE f32->bf16 pair pack (a -> low16, b -> high16)
__device__ __forceinline__ unsigned int pack_bf16x2(float a, float b) {
    unsigned int ua = __float_as_uint(a), ub = __float_as_uint(b);
    ua = (ua + 0x7FFFu + ((ua >> 16) & 1u)) >> 16;
    ub = (ub + 0x7FFFu + ((ub >> 16) & 1u)) & 0xFFFF0000u;
    return ua | ub;
}

// ---------- embW[v][j] = emb[v]@W1[:,j] + b1[j]; 8 words per block ----------
__global__ __launch_bounds__(256) void embW_kernel(
    const float* __restrict__ emb, const float* __restrict__ W1,
    const float* __restrict__ b1, float* __restrict__ embW)
{
    const int v0 = blockIdx.x * 8;
    const int j = threadIdx.x;
    const float bj = b1[j];
    float acc[8];
    #pragma unroll
    for (int v = 0; v < 8; ++v) acc[v] = bj;
    #pragma unroll 2
    for (int k = 0; k < EMBED_LEN; ++k) {
        const float wk = W1[k * 256 + j];
        #pragma unroll
        for (int v = 0; v < 8; ++v)
            acc[v] = fmaf(emb[(v0 + v) * EMBED_LEN + k], wk, acc[v]);
    }
    #pragma unroll
    for (int v = 0; v < 8; ++v)
        embW[(size_t)(v0 + v) * 256 + j] = acc[v];
}

// ---------- repack U1,W2,U2 (f32 [64][256]) -> bf16 A-fragment-linear ----------
// element e = ((tau*2+kt)*64 + lane)*8 + j8 holds bf16( M[kt*32 + (lane>>4)*8 + j8][tau*16 + (lane&15)] )
__global__ __launch_bounds__(256) void repack_kernel(
    const float* __restrict__ U1, const float* __restrict__ W2,
    const float* __restrict__ U2, unsigned short* __restrict__ wr)
{
    const int e = blockIdx.x * 256 + threadIdx.x;          // 0..16383
    const float* src = (blockIdx.y == 0) ? U1 : ((blockIdx.y == 1) ? W2 : U2);
    const int j8 = e & 7;
    const int l  = (e >> 3) & 63;
    const int kt = (e >> 9) & 1;
    const int tau = e >> 10;
    const int k = kt * 32 + (l >> 4) * 8 + j8;
    const int j = tau * 16 + (l & 15);
    unsigned int u = __float_as_uint(src[k * 256 + j]);
    u = (u + 0x7FFFu + ((u >> 16) & 1u)) >> 16;
    wr[blockIdx.y * 16384 + e] = (unsigned short)u;
}

// ---------- main recurrence (V3) ----------
// 16 samples/block, 8 waves (512 thr) = 2 waves/SIMD. Wave w owns output
// tiles {2w, 2w+1} (MFMA only); z goes through LDS f32; activation is
// split evenly: lane does units u0=w*8+q*2, u0+1 at its sample m.
// h1/h2 double-buffered bf16 LDS; 4 barriers/step.
__global__ __launch_bounds__(512) void lstm_main(
    const int*   __restrict__ tokens,
    const float* __restrict__ embW,
    const unsigned short* __restrict__ wr,
    const float* __restrict__ b2,
    const float* __restrict__ Wo,
    const float* __restrict__ bo,
    float*       __restrict__ out)
{
    __shared__ unsigned short h1b[2][1152];   // [buf][m*72+u]
    __shared__ unsigned short h2b[2][1152];
    __shared__ float zb[16 * 260];            // z [m][260-padded j]
    __shared__ float padf[128];

    const int tid = threadIdx.x;
    const int l = tid & 63;
    const int w = tid >> 6;                   // wave 0..7
    const int m = l & 15, q = l >> 4;
    const int b0 = blockIdx.x * 16;
    const int hrow = m * 72;
    const int u0 = w * 8 + q * 2;             // this lane's act units: u0, u0+1
    const int zrow = m * 260;

    // zero h buffers
    for (int i = tid; i < 1152; i += 512) {
        ((unsigned int*)h1b)[i] = 0u;
        ((unsigned int*)h2b)[i] = 0u;
    }

    // ---- weight fragments for tiles tau = 2w, 2w+1 (one-time) ----
    short8 a1w[2][2], w2w[2][2], u2w[2][2];   // [ti][kt]
    #pragma unroll
    for (int ti = 0; ti < 2; ++ti) {
        #pragma unroll
        for (int kt = 0; kt < 2; ++kt) {
            const int off = ((2 * w + ti) * 2 + kt) * 512 + l * 8;
            a1w[ti][kt] = *(const short8*)(wr +         off);
            w2w[ti][kt] = *(const short8*)(wr + 16384 + off);
            u2w[ti][kt] = *(const short8*)(wr + 32768 + off);
        }
    }
    floatx4 b2f[2];
    #pragma unroll
    for (int ti = 0; ti < 2; ++ti)
        b2f[ti] = *(const floatx4*)(b2 + (2 * w + ti) * 16 + 4 * q);

    float c1[2] = {}, c2[2] = {}, h2s[2] = {};

    // t=0 seed gather (cold) + token prefetch
    const int tok0 = tokens[(b0 + m) * SEQ_LEN + 0];
    floatx4 xb[2];
    #pragma unroll
    for (int ti = 0; ti < 2; ++ti)
        xb[ti] = *(const floatx4*)(embW + (size_t)tok0 * 256 + (2 * w + ti) * 16 + 4 * q);
    int tokN = tokens[(b0 + m) * SEQ_LEN + 1];

    __syncthreads();   // h buffers zeroed

    auto step = [&](const unsigned short* h1p, unsigned short* h1c,
                    const unsigned short* h2p, unsigned short* h2c, int t) {
        // seed acc1 with prefetched x@W1+b1; prefetch next
        floatx4 acc1[2];
        #pragma unroll
        for (int ti = 0; ti < 2; ++ti) acc1[ti] = xb[ti];
        #pragma unroll
        for (int ti = 0; ti < 2; ++ti)
            xb[ti] = *(const floatx4*)(embW + (size_t)tokN * 256 + (2 * w + ti) * 16 + 4 * q);
        {
            const int tn2 = (t + 2 < SEQ_LEN) ? t + 2 : SEQ_LEN - 1;
            tokN = tokens[(b0 + m) * SEQ_LEN + tn2];
        }

        // ---- layer1 MFMA: acc1 += U1^T @ h1(t-1)^T ----
        {
            const short8 hb0 = *(const short8*)(h1p + hrow + 0  + q * 8);
            const short8 hb1 = *(const short8*)(h1p + hrow + 32 + q * 8);
            #pragma unroll
            for (int ti = 0; ti < 2; ++ti) {
                acc1[ti] = __builtin_amdgcn_mfma_f32_16x16x32_bf16(a1w[ti][0], hb0, acc1[ti], 0, 0, 0);
                acc1[ti] = __builtin_amdgcn_mfma_f32_16x16x32_bf16(a1w[ti][1], hb1, acc1[ti], 0, 0, 0);
            }
        }
        // ---- U2 @ h2(t-1) early (independent of h1(t)) ----
        floatx4 acc2[2];
        {
            const short8 hc0 = *(const short8*)(h2p + hrow + 0  + q * 8);
            const short8 hc1 = *(const short8*)(h2p + hrow + 32 + q * 8);
            #pragma unroll
            for (int ti = 0; ti < 2; ++ti) {
                floatx4 a = b2f[ti];
                a = __builtin_amdgcn_mfma_f32_16x16x32_bf16(u2w[ti][0], hc0, a, 0, 0, 0);
                a = __builtin_amdgcn_mfma_f32_16x16x32_bf16(u2w[ti][1], hc1, a, 0, 0, 0);
                acc2[ti] = a;
            }
        }
        // z1 -> LDS
        #pragma unroll
        for (int ti = 0; ti < 2; ++ti)
            *(floatx4*)&zb[zrow + (2 * w + ti) * 16 + 4 * q] = acc1[ti];
        __syncthreads();

        // ---- act1: lane does (u0, u0+1) at sample m ----
        {
            const float2 zi = *(const float2*)&zb[zrow +   0 + u0];
            const float2 zf = *(const float2*)&zb[zrow +  64 + u0];
            const float2 zg = *(const float2*)&zb[zrow + 128 + u0];
            const float2 zo = *(const float2*)&zb[zrow + 192 + u0];
            float hn[2];
            #pragma unroll
            for (int p = 0; p < 2; ++p) {
                const float iv = fast_sigmoid(p ? zi.y : zi.x);
                const float fv = fast_sigmoid(p ? zf.y : zf.x);
                const float gv = fast_tanh   (p ? zg.y : zg.x);
                const float ov = fast_sigmoid(p ? zo.y : zo.x);
                const float cn = fmaf(fv, c1[p], iv * gv);
                c1[p] = cn;
                hn[p] = ov * fast_tanh(cn);
            }
            *(unsigned int*)(h1c + m * 72 + u0) = pack_bf16x2(hn[0], hn[1]);
        }
        __syncthreads();   // h1(t) ready

        // ---- layer2 MFMA: acc2 += W2^T @ h1(t)^T ----
        {
            const short8 hA0 = *(const short8*)(h1c + hrow + 0  + q * 8);
            const short8 hA1 = *(const short8*)(h1c + hrow + 32 + q * 8);
            #pragma unroll
            for (int ti = 0; ti < 2; ++ti) {
                acc2[ti] = __builtin_amdgcn_mfma_f32_16x16x32_bf16(w2w[ti][0], hA0, acc2[ti], 0, 0, 0);
                acc2[ti] = __builtin_amdgcn_mfma_f32_16x16x32_bf16(w2w[ti][1], hA1, acc2[ti], 0, 0, 0);
            }
        }
        #pragma unroll
        for (int ti = 0; ti < 2; ++ti)
            *(floatx4*)&zb[zrow + (2 * w + ti) * 16 + 4 * q] = acc2[ti];
        __syncthreads();

        // ---- act2 ----
        {
            const float2 zi = *(const float2*)&zb[zrow +   0 + u0];
            const float2 zf = *(const float2*)&zb[zrow +  64 + u0];
            const float2 zg = *(const float2*)&zb[zrow + 128 + u0];
            const float2 zo = *(const float2*)&zb[zrow + 192 + u0];
            float hn[2];
            #pragma unroll
            for (int p = 0; p < 2; ++p) {
                const float iv = fast_sigmoid(p ? zi.y : zi.x);
                const float fv = fast_sigmoid(p ? zf.y : zf.x);
                const float gv = fast_tanh   (p ? zg.y : zg.x);
                const float ov = fast_sigmoid(p ? zo.y : zo.x);
                const float cn = fmaf(fv, c2[p], iv * gv);
                c2[p] = cn;
                hn[p] = ov * fast_tanh(cn);
            }
            h2s[0] = hn[0]; h2s[1] = hn[1];
            *(unsigned int*)(h2c + m * 72 + u0) = pack_bf16x2(hn[0], hn[1]);
        }
        __syncthreads();   // h2(t) ready
    };

    for (int t = 0; t < SEQ_LEN; t += 2) {
        step(h1b[1], h1b[0], h2b[1], h2b[0], t);       // even t
        step(h1b[0], h1b[1], h2b[0], h2b[1], t + 1);   // odd t
    }

    // ---- output: sigmoid(h2 @ Wo + bo) ----
    float part = h2s[0] * Wo[u0] + h2s[1] * Wo[u0 + 1];
    part += __shfl_xor(part, 16, 64);
    part += __shfl_xor(part, 32, 64);   // sum over q within wave
    if (l < 16) padf[w * 16 + m] = part;
    __syncthreads();
    if (tid < 16) {
        float dot = 0.f;
        #pragma unroll
        for (int k = 0; k < 8; ++k) dot += padf[k * 16 + tid];
        out[b0 + tid] = fast_sigmoid(dot + bo[0]);
    }
}

extern "C" void kernel_launch(void* const* d_in, const int* in_sizes, int n_in,
                              void* d_out, int out_size, void* d_ws, size_t ws_size,
                              hipStream_t stream) {
    const int*   tokens = (const int*)  d_in[0];
    const float* emb    = (const float*)d_in[1];
    const float* W1     = (const float*)d_in[2];
    const float* U1     = (const float*)d_in[3];
    const float* b1     = (const float*)d_in[4];   // folded into embW
    const float* W2     = (const float*)d_in[5];
    const float* U2     = (const float*)d_in[6];
    const float* b2     = (const float*)d_in[7];
    const float* Wo     = (const float*)d_in[8];
    const float* bo     = (const float*)d_in[9];
    float* out = (float*)d_out;

    char* ws = (char*)d_ws;
    float*          embWp = (float*)ws;                       // 10,240,000 B
    unsigned short* wrep  = (unsigned short*)(ws + 10240000); // 98,304 B
    (void)b1; (void)in_sizes; (void)n_in; (void)out_size; (void)ws_size;

    embW_kernel<<<TOTAL_WORDS / 8, 256, 0, stream>>>(emb, W1, b1, embWp);
    repack_kernel<<<dim3(64, 3), 256, 0, stream>>>(U1, W2, U2, wrep);
    lstm_main<<<BATCH / 16, 512, 0, stream>>>(tokens, embWp, wrep, b2, Wo, bo, out);
}